// Round 1
// baseline (1168.301 us; speedup 1.0000x reference)
//
#include <hip/hip_runtime.h>
#include <hip/hip_bf16.h>

#define M_DIM 4096
#define N_DIM 8192
#define K_DIM 8192

using bf16x8 = __attribute__((ext_vector_type(8))) short;
using f32x4  = __attribute__((ext_vector_type(4))) float;

static __device__ __forceinline__ unsigned short f32_to_bf16_rne(float f) {
    unsigned u = __float_as_uint(f);
    unsigned rounding = 0x7FFFu + ((u >> 16) & 1u);
    u += rounding;
    return (unsigned short)(u >> 16);
}

// ---------------- zero W (f32) ----------------
__global__ void zero_kernel(float4* __restrict__ p, int n4) {
    int i = blockIdx.x * blockDim.x + threadIdx.x;
    int stride = gridDim.x * blockDim.x;
    float4 z = make_float4(0.f, 0.f, 0.f, 0.f);
    for (; i < n4; i += stride) p[i] = z;
}

// ---------------- scatter-add COO ----------------
__global__ void scatter_kernel(const float* __restrict__ vals,
                               const int* __restrict__ rows,
                               const int* __restrict__ cols,
                               float* __restrict__ W, int n) {
    int i = blockIdx.x * blockDim.x + threadIdx.x;
    if (i < n) {
        atomicAdd(&W[(size_t)rows[i] * K_DIM + cols[i]], vals[i]);
    }
}

// ---------------- f32 -> bf16 cast ----------------
__global__ void cvt_bf16_kernel(const float4* __restrict__ src,
                                ushort4* __restrict__ dst, int n4) {
    int i = blockIdx.x * blockDim.x + threadIdx.x;
    int stride = gridDim.x * blockDim.x;
    for (; i < n4; i += stride) {
        float4 v = src[i];
        ushort4 o;
        o.x = f32_to_bf16_rne(v.x);
        o.y = f32_to_bf16_rne(v.y);
        o.z = f32_to_bf16_rne(v.z);
        o.w = f32_to_bf16_rne(v.w);
        dst[i] = o;
    }
}

// ---------------- zero d_out fallback (ws too small diagnostic) ----------------
__global__ void zero_out_kernel(float* __restrict__ p, int n) {
    int i = blockIdx.x * blockDim.x + threadIdx.x;
    int stride = gridDim.x * blockDim.x;
    for (; i < n; i += stride) p[i] = 0.f;
}

// ---------------- bf16 NT GEMM: C[M][N] = A[M][K] * B[N][K]^T ----------------
// 128x128 tile, BK=32, 4 waves (2x2), each wave 64x64 via 4x4 16x16x32 MFMAs.
__global__ __launch_bounds__(256) void gemm_bt(const ushort* __restrict__ A,
                                               const ushort* __restrict__ B,
                                               float* __restrict__ C) {
    constexpr int BM = 128, BN = 128, BK = 32;
    __shared__ ushort As[BM][BK];  // 8 KB
    __shared__ ushort Bs[BN][BK];  // 8 KB

    const int nbn = N_DIM / BN;            // 64
    const int bm = blockIdx.x / nbn;
    const int bn = blockIdx.x % nbn;
    const int brow = bm * BM, bcol = bn * BN;

    const int t = threadIdx.x;
    const int lane = t & 63;
    const int w = t >> 6;                  // wave 0..3
    const int wm = w >> 1, wn = w & 1;     // 2x2 wave grid
    const int lrow = lane & 15;            // fragment row within 16
    const int k8 = (lane >> 4) * 8;        // fragment k offset

    f32x4 acc[4][4] = {};

    for (int kt = 0; kt < K_DIM; kt += BK) {
        // ---- stage A and B tiles: 512 x 16B chunks each tile-half ----
        // flat chunk index fl -> LDS bytes [fl*16, fl*16+16): per-wave lanes
        // are contiguous (base + lane*16), satisfying global_load_lds's
        // linear-dest requirement.
        #pragma unroll
        for (int c = 0; c < 2; ++c) {
            int fl = c * 256 + t;          // 0..511
            int row = fl >> 2;             // 4 chunks (32 bf16) per row
            int kk = (fl & 3) * 8;
            const ushort* ga = A + (size_t)(brow + row) * K_DIM + kt + kk;
            __builtin_amdgcn_global_load_lds(
                (const __attribute__((address_space(1))) void*)ga,
                (__attribute__((address_space(3))) void*)(&As[0][0] + fl * 8),
                16, 0, 0);
            const ushort* gb = B + (size_t)(bcol + row) * K_DIM + kt + kk;
            __builtin_amdgcn_global_load_lds(
                (const __attribute__((address_space(1))) void*)gb,
                (__attribute__((address_space(3))) void*)(&Bs[0][0] + fl * 8),
                16, 0, 0);
        }
        __syncthreads();

        bf16x8 af[4], bfr[4];
        #pragma unroll
        for (int m = 0; m < 4; ++m)
            af[m] = *(const bf16x8*)&As[wm * 64 + m * 16 + lrow][k8];
        #pragma unroll
        for (int n = 0; n < 4; ++n)
            bfr[n] = *(const bf16x8*)&Bs[wn * 64 + n * 16 + lrow][k8];

        #pragma unroll
        for (int m = 0; m < 4; ++m)
            #pragma unroll
            for (int n = 0; n < 4; ++n)
                acc[m][n] = __builtin_amdgcn_mfma_f32_16x16x32_bf16(
                    af[m], bfr[n], acc[m][n], 0, 0, 0);
        __syncthreads();
    }

    // ---- epilogue: C/D layout col=lane&15, row=(lane>>4)*4+r ----
    const int crow0 = brow + wm * 64;
    const int ccol0 = bcol + wn * 64;
    #pragma unroll
    for (int m = 0; m < 4; ++m) {
        #pragma unroll
        for (int n = 0; n < 4; ++n) {
            int col = ccol0 + n * 16 + (lane & 15);
            int rbase = crow0 + m * 16 + (lane >> 4) * 4;
            #pragma unroll
            for (int r = 0; r < 4; ++r)
                C[(size_t)(rbase + r) * N_DIM + col] = acc[m][n][r];
        }
    }
}

extern "C" void kernel_launch(void* const* d_in, const int* in_sizes, int n_in,
                              void* d_out, int out_size, void* d_ws, size_t ws_size,
                              hipStream_t stream) {
    const float* x    = (const float*)d_in[0];
    const float* vals = (const float*)d_in[1];
    const int* rows   = (const int*)d_in[2];
    const int* cols   = (const int*)d_in[3];
    float* out        = (float*)d_out;
    const int n_items = in_sizes[1];

    const size_t W_F32_BYTES  = (size_t)N_DIM * K_DIM * 4;  // 256 MiB
    const size_t W_BF16_BYTES = (size_t)N_DIM * K_DIM * 2;  // 128 MiB
    const size_t X_BF16_BYTES = (size_t)M_DIM * K_DIM * 2;  //  64 MiB
    const size_t NEEDED = W_F32_BYTES + W_BF16_BYTES + X_BF16_BYTES;

    if (ws_size < NEEDED) {
        // Diagnostic fallback: clean absmax=126 failure signals ws too small.
        zero_out_kernel<<<2048, 256, 0, stream>>>(out, out_size);
        return;
    }

    char* ws = (char*)d_ws;
    float* Wf  = (float*)ws;
    ushort* Wb = (ushort*)(ws + W_F32_BYTES);
    ushort* Xb = (ushort*)(ws + W_F32_BYTES + W_BF16_BYTES);

    // 1) zero W (re-zeroed every call: deterministic under replay)
    zero_kernel<<<2048, 256, 0, stream>>>((float4*)Wf, (N_DIM * K_DIM) / 4);
    // 2) scatter-add nonzeros
    scatter_kernel<<<(n_items + 255) / 256, 256, 0, stream>>>(vals, rows, cols, Wf, n_items);
    // 3) cast W and x to bf16
    cvt_bf16_kernel<<<2048, 256, 0, stream>>>((const float4*)Wf, (ushort4*)Wb,
                                              (N_DIM * K_DIM) / 4);
    cvt_bf16_kernel<<<2048, 256, 0, stream>>>((const float4*)x, (ushort4*)Xb,
                                              (M_DIM * K_DIM) / 4);
    // 4) GEMM: out = Xb (M x K) * Wb (N x K)^T
    gemm_bt<<<(M_DIM / 128) * (N_DIM / 128), 256, 0, stream>>>(Xb, Wb, out);
}